// Round 17
// baseline (19.511 us; speedup 1.0000x reference)
//
#include <hip/hip_runtime.h>

// GARCH(1,1) paths, 3 series, N = 24*131072.
//   v_t = omega + alpha*p_{t-1}^2 + beta*v_{t-1};  p_t = mu + z_t*sqrt(v_t); p_0=0.
// out[s*N + t] = p_t.
//
// R16 = R15 with OPL 16 -> 8 (spine halves again; 18432 short waves pipeline
// across 2.25 residency rounds; VGPR ~48 -> full 8 waves/SIMD).
// Warm (512 steps) now amortized per 512 outputs -- extra z re-reads are
// L2/L3-resident, warm instr ~50/wave.
//
// Structure (R13..R15): per wave (512 outputs), lane l owns 8 at O = 512w+8l.
//  - mu <= 0.001 => dropping the 2*alpha*mu*z*sv cross-term makes the
//    v-recurrence LINEAR: v_{t+1} = c2(z_t)*v_t + w0. Lane composes its
//    8-step affine map; 6-shfl wave scan; exclusive prefix = map over
//    [512w, O) exactly (no bridge). Warm (w>0): 512 steps wave-scanned from
//    the steady guess; w==0 exact from v_0=0 (only p_0 special-cased).
//  - Coalesced global access via wave-private 2KB LDS transpose, XOR swizzle
//    S^((S>>3)&7) (involution; verified conflict-free at read stride 2).
//  - Output: lag-2 sv cross-term (v-chain = 1 fma/step, sqrt off-chain;
//    error ~4e-5/step), p uses exact current sv. NT full-line stores.

#define NSER 3
#define OPL  8                     // outputs per lane
#define OPW  (64 * OPL)            // 512 outputs per wave
#define QPW  (OPW / 4)             // 128 quads per wave
#define WPB  4                     // waves per block
#define TPB  256
#define WARM 512

typedef float f32x4 __attribute__((ext_vector_type(4)));

__device__ __forceinline__ int SWZ(int S) { return S ^ ((S >> 3) & 7); }

__global__ __launch_bounds__(TPB) void garch_kernel(
    const float* __restrict__ params,   // (3,4): [mu, omega, alpha, beta]
    const float* __restrict__ noise,    // (3,N)
    float* __restrict__ out,            // (3,N)
    int N)
{
    __shared__ __align__(16) float4 Wq[WPB * QPW];     // 8,192 B

    const int tid  = threadIdx.x;
    const int ln   = tid & 63;
    const int wv   = tid >> 6;
    const int nwps = N / OPW;                          // 6144 waves per series
    const int gw   = blockIdx.x * WPB + wv;
    const int s    = gw / nwps;
    const int w    = gw - s * nwps;

    const float mu    = params[s * 4 + 0];
    const float omega = params[s * 4 + 1];
    const float alpha = params[s * 4 + 2];
    const float beta  = params[s * 4 + 3];
    const float w0 = fmaf(alpha, mu * mu, omega);
    const float k1 = 2.0f * alpha * mu;
    const float vg = omega / fmaxf(1.0f - alpha - beta, 0.02f);

    const float4* z4 = (const float4*)(noise + (size_t)s * N);
    const int gq0 = (OPW * w) >> 2;                    // wave's first main quad
    float4* WB = &Wq[QPW * wv];                        // wave-private region

    // ---- stage main z: coalesced 1KB wave-loads -> swizzled LDS -----------
    #pragma unroll
    for (int i = 0; i < 2; ++i)
        WB[SWZ(64 * i + ln)] = z4[gq0 + 64 * i + ln];

    // ---- warm map (w>0): 512 steps across the wave (32B/lane, coalesced) --
    float vws = 0.0f;                                  // w==0: exact v_0 = 0
    if (w > 0) {
        const int qb = (OPW * w - WARM) >> 2;
        float4 q0 = z4[qb + 2 * ln], q1 = z4[qb + 2 * ln + 1];
        float Aw = 1.0f, Bw = 0.0f, c;
        #define WSTEP(Z) { c = fmaf(alpha, (Z)*(Z), beta); Aw *= c; Bw = fmaf(c, Bw, w0); }
        WSTEP(q0.x); WSTEP(q0.y); WSTEP(q0.z); WSTEP(q0.w);
        WSTEP(q1.x); WSTEP(q1.y); WSTEP(q1.z); WSTEP(q1.w);
        #undef WSTEP
        #pragma unroll
        for (int d = 1; d < 64; d <<= 1) {             // inclusive scan
            float Ap = __shfl_up(Aw, d), Bp = __shfl_up(Bw, d);
            if (ln >= d) { Bw = fmaf(Aw, Bp, Bw); Aw *= Ap; }
        }
        float Af = __shfl(Aw, 63), Bf = __shfl(Bw, 63);
        vws = fmaf(Af, vg, Bf);                        // v at wave start
    }

    // ---- lane's contiguous 8 z from LDS (conflict-free b128) --------------
    float4 zr[2];
    #pragma unroll
    for (int j = 0; j < 2; ++j) zr[j] = WB[SWZ(2 * ln + j)];

    // ---- lane segment map over [O, O+8), scan, exclusive prefix -----------
    float A = 1.0f, B = 0.0f;
    #pragma unroll
    for (int i = 0; i < 2; ++i) {
        float c;
        #define CSTEP(Z) { c = fmaf(alpha, (Z)*(Z), beta); A *= c; B = fmaf(c, B, w0); }
        CSTEP(zr[i].x); CSTEP(zr[i].y); CSTEP(zr[i].z); CSTEP(zr[i].w);
        #undef CSTEP
    }
    #pragma unroll
    for (int d = 1; d < 64; d <<= 1) {                 // inclusive scan
        float Ap = __shfl_up(A, d), Bp = __shfl_up(B, d);
        if (ln >= d) { B = fmaf(A, Bp, B); A *= Ap; }
    }
    float Ax = __shfl_up(A, 1), Bx = __shfl_up(B, 1);  // exclusive prefix
    if (ln == 0) { Ax = 1.0f; Bx = 0.0f; }
    float v  = fmaf(Ax, vws, Bx);                      // v at O

    // ---- exact output: 8 steps; v-chain = 1 fma/step (lag-2 sv) -----------
    float s0 = __builtin_amdgcn_sqrtf(v);              // sqrt(v_j), j = 0
    float s1 = s0, s2 = s0;                            // lag history (approx)
    #pragma unroll
    for (int i = 0; i < 2; ++i) {
        #define OSTEP(E) { float z_ = zr[i].E;                               \
            float p_    = fmaf(z_, s0, mu);            /* p_j = z*sv_j + mu */\
            float base_ = fmaf(k1 * z_, s2, w0);       /* cross-term, lag-2 */\
            float c2_   = fmaf(alpha, z_ * z_, beta);                        \
            v  = fmaf(c2_, v, base_);                  /* 4-cy chain */      \
            s2 = s1; s1 = s0;                                                \
            s0 = __builtin_amdgcn_sqrtf(v);            /* off-chain */       \
            zr[i].E = p_; }
        OSTEP(x); OSTEP(y); OSTEP(z); OSTEP(w);
        #undef OSTEP
    }
    if (w == 0 && ln == 0) zr[0].x = 0.0f;             // p_0 = 0 exactly

    // ---- store transpose: p -> LDS (region is dead) -> coalesced NT stores
    #pragma unroll
    for (int j = 0; j < 2; ++j) WB[SWZ(2 * ln + j)] = zr[j];

    float4* o4 = (float4*)(out + (size_t)s * N) + gq0;
    #pragma unroll
    for (int i = 0; i < 2; ++i) {
        float4 val = WB[SWZ(64 * i + ln)];
        __builtin_nontemporal_store(*(f32x4*)&val,     // output never re-read
                                    (f32x4*)&o4[64 * i + ln]);
    }
}

extern "C" void kernel_launch(void* const* d_in, const int* in_sizes, int n_in,
                              void* d_out, int out_size, void* d_ws, size_t ws_size,
                              hipStream_t stream) {
    const float* params = (const float*)d_in[0];
    const float* noise  = (const float*)d_in[1];
    float* out = (float*)d_out;

    const int N = in_sizes[1] / NSER;                  // 3,145,728
    const int grid = NSER * (N / OPW) / WPB;           // 4608 blocks (18432 waves)

    garch_kernel<<<grid, TPB, 0, stream>>>(params, noise, out, N);
}

// Round 18
// 17.746 us; speedup vs baseline: 1.0995x; 1.0995x over previous
//
#include <hip/hip_runtime.h>

// GARCH(1,1) paths, 3 series, N = 24*131072.
//   v_t = omega + alpha*p_{t-1}^2 + beta*v_{t-1};  p_t = mu + z_t*sqrt(v_t); p_0=0.
// out[s*N + t] = p_t.
//
// R17 = R15 (OPL=16, the measured optimum: R14 OPL32=20.5, R15 OPL16=17.9,
// R16 OPL8=19.5) + WARM 512->384 (warm is pure overhead; 384 steps leave
// ~1e-4 of the <=24x initial mis-guess even at +5 sigma worst-case params --
// R8/R9 ran WARM=384 safely). Warm loads: 3 x float2 per lane (6 z).
//
// Structure: per wave (1024 outputs), lane l owns 16 at O = 1024w + 16l.
//  - mu <= 0.001 => dropping the 2*alpha*mu*z*sv cross-term makes the
//    v-recurrence LINEAR: v_{t+1} = c2(z_t)*v_t + w0. Lane composes its
//    16-step affine map; 6-shfl wave scan; exclusive prefix = map over
//    [1024w, O) exactly (no bridge). Warm (w>0): 384 steps wave-scanned from
//    the steady guess; w==0 exact from v_0=0 (only p_0 special-cased).
//  - Coalesced global access via wave-private 4KB LDS transpose, XOR swizzle
//    S^((S>>3)&7) (involution, conflict-free both phases, no barriers).
//  - Output: lag-2 sv cross-term (v-chain = 1 fma/step, sqrt off-chain;
//    error ~4e-5/step), p uses exact current sv. NT full-line stores.

#define NSER 3
#define OPL  16                    // outputs per lane
#define OPW  (64 * OPL)            // 1024 outputs per wave
#define QPW  (OPW / 4)             // 256 quads per wave
#define WPB  4                     // waves per block
#define TPB  256
#define WARM 384

typedef float f32x4 __attribute__((ext_vector_type(4)));

__device__ __forceinline__ int SWZ(int S) { return S ^ ((S >> 3) & 7); }

__global__ __launch_bounds__(TPB) void garch_kernel(
    const float* __restrict__ params,   // (3,4): [mu, omega, alpha, beta]
    const float* __restrict__ noise,    // (3,N)
    float* __restrict__ out,            // (3,N)
    int N)
{
    __shared__ __align__(16) float4 Wq[WPB * QPW];     // 16,384 B

    const int tid  = threadIdx.x;
    const int ln   = tid & 63;
    const int wv   = tid >> 6;
    const int nwps = N / OPW;                          // 3072 waves per series
    const int gw   = blockIdx.x * WPB + wv;
    const int s    = gw / nwps;
    const int w    = gw - s * nwps;

    const float mu    = params[s * 4 + 0];
    const float omega = params[s * 4 + 1];
    const float alpha = params[s * 4 + 2];
    const float beta  = params[s * 4 + 3];
    const float w0 = fmaf(alpha, mu * mu, omega);
    const float k1 = 2.0f * alpha * mu;
    const float vg = omega / fmaxf(1.0f - alpha - beta, 0.02f);

    const float4* z4 = (const float4*)(noise + (size_t)s * N);
    const int gq0 = (OPW * w) >> 2;                    // wave's first main quad
    float4* WB = &Wq[QPW * wv];                        // wave-private region

    // ---- stage main z: coalesced 1KB wave-loads -> swizzled LDS -----------
    #pragma unroll
    for (int i = 0; i < 4; ++i)
        WB[SWZ(64 * i + ln)] = z4[gq0 + 64 * i + ln];

    // ---- warm map (w>0): 384 steps across the wave (6 z/lane, 3x float2) --
    float vws = 0.0f;                                  // w==0: exact v_0 = 0
    if (w > 0) {
        const float2* z2 = (const float2*)(noise + (size_t)s * N);
        const int fb = ((OPW * w - WARM) >> 1) + 3 * ln;
        float2 qa = z2[fb], qb = z2[fb + 1], qc = z2[fb + 2];
        float Aw = 1.0f, Bw = 0.0f, c;
        #define WSTEP(Z) { c = fmaf(alpha, (Z)*(Z), beta); Aw *= c; Bw = fmaf(c, Bw, w0); }
        WSTEP(qa.x); WSTEP(qa.y);
        WSTEP(qb.x); WSTEP(qb.y);
        WSTEP(qc.x); WSTEP(qc.y);
        #undef WSTEP
        #pragma unroll
        for (int d = 1; d < 64; d <<= 1) {             // inclusive scan
            float Ap = __shfl_up(Aw, d), Bp = __shfl_up(Bw, d);
            if (ln >= d) { Bw = fmaf(Aw, Bp, Bw); Aw *= Ap; }
        }
        float Af = __shfl(Aw, 63), Bf = __shfl(Bw, 63);
        vws = fmaf(Af, vg, Bf);                        // v at wave start
    }

    // ---- lane's contiguous 16 z from LDS (conflict-free b128) -------------
    float4 zr[4];
    #pragma unroll
    for (int j = 0; j < 4; ++j) zr[j] = WB[SWZ(4 * ln + j)];

    // ---- lane segment map over [O, O+16), scan, exclusive prefix ----------
    float A = 1.0f, B = 0.0f;
    #pragma unroll
    for (int i = 0; i < 4; ++i) {
        float c;
        #define CSTEP(Z) { c = fmaf(alpha, (Z)*(Z), beta); A *= c; B = fmaf(c, B, w0); }
        CSTEP(zr[i].x); CSTEP(zr[i].y); CSTEP(zr[i].z); CSTEP(zr[i].w);
        #undef CSTEP
    }
    #pragma unroll
    for (int d = 1; d < 64; d <<= 1) {                 // inclusive scan
        float Ap = __shfl_up(A, d), Bp = __shfl_up(B, d);
        if (ln >= d) { B = fmaf(A, Bp, B); A *= Ap; }
    }
    float Ax = __shfl_up(A, 1), Bx = __shfl_up(B, 1);  // exclusive prefix
    if (ln == 0) { Ax = 1.0f; Bx = 0.0f; }
    float v  = fmaf(Ax, vws, Bx);                      // v at O

    // ---- exact output: 16 steps; v-chain = 1 fma/step (lag-2 sv) ----------
    float s0 = __builtin_amdgcn_sqrtf(v);              // sqrt(v_j), j = 0
    float s1 = s0, s2 = s0;                            // lag history (approx)
    #pragma unroll
    for (int i = 0; i < 4; ++i) {
        #define OSTEP(E) { float z_ = zr[i].E;                               \
            float p_    = fmaf(z_, s0, mu);            /* p_j = z*sv_j + mu */\
            float base_ = fmaf(k1 * z_, s2, w0);       /* cross-term, lag-2 */\
            float c2_   = fmaf(alpha, z_ * z_, beta);                        \
            v  = fmaf(c2_, v, base_);                  /* 4-cy chain */      \
            s2 = s1; s1 = s0;                                                \
            s0 = __builtin_amdgcn_sqrtf(v);            /* off-chain */       \
            zr[i].E = p_; }
        OSTEP(x); OSTEP(y); OSTEP(z); OSTEP(w);
        #undef OSTEP
    }
    if (w == 0 && ln == 0) zr[0].x = 0.0f;             // p_0 = 0 exactly

    // ---- store transpose: p -> LDS (region is dead) -> coalesced NT stores
    #pragma unroll
    for (int j = 0; j < 4; ++j) WB[SWZ(4 * ln + j)] = zr[j];

    float4* o4 = (float4*)(out + (size_t)s * N) + gq0;
    #pragma unroll
    for (int i = 0; i < 4; ++i) {
        float4 val = WB[SWZ(64 * i + ln)];
        __builtin_nontemporal_store(*(f32x4*)&val,     // output never re-read
                                    (f32x4*)&o4[64 * i + ln]);
    }
}

extern "C" void kernel_launch(void* const* d_in, const int* in_sizes, int n_in,
                              void* d_out, int out_size, void* d_ws, size_t ws_size,
                              hipStream_t stream) {
    const float* params = (const float*)d_in[0];
    const float* noise  = (const float*)d_in[1];
    float* out = (float*)d_out;

    const int N = in_sizes[1] / NSER;                  // 3,145,728
    const int grid = NSER * (N / OPW) / WPB;           // 2304 blocks (9216 waves)

    garch_kernel<<<grid, TPB, 0, stream>>>(params, noise, out, N);
}